// Round 1
// baseline (2751.721 us; speedup 1.0000x reference)
//
#include <hip/hip_runtime.h>

typedef unsigned short ushort_t;
typedef __attribute__((ext_vector_type(8))) short bf16x8;
typedef __attribute__((ext_vector_type(4))) float f32x4;
typedef __attribute__((ext_vector_type(4))) unsigned short us4;

#define DEV __device__ __forceinline__

DEV ushort_t f2b(float f) {
    union { float f; unsigned u; } x; x.f = f;
    unsigned r = (x.u + 0x7fffu + ((x.u >> 16) & 1u)) >> 16;
    return (ushort_t)r;
}

typedef void __attribute__((address_space(1)))* gp1;
typedef void __attribute__((address_space(3)))* sp3;
DEV void gload_lds16(const void* g, void* l) {
    __builtin_amdgcn_global_load_lds((gp1)g, (sp3)l, 16, 0, 0);
}

// ---------------- weight prep: f32 [K][N] -> bf16 [N][K] ----------------
__global__ __launch_bounds__(256) void transpose_cvt(
    const float* __restrict__ in, ushort_t* __restrict__ out, int K, int N)
{
    __shared__ float tile[32][33];
    const int nb = blockIdx.z;
    const float* src = in + (size_t)nb * K * N;
    ushort_t* dst = out + (size_t)nb * K * N;
    const int n0 = blockIdx.x * 32, k0 = blockIdx.y * 32;
    const int tx = threadIdx.x & 31, ty = threadIdx.x >> 5;
#pragma unroll
    for (int i = 0; i < 32; i += 8)
        tile[ty + i][tx] = src[(size_t)(k0 + ty + i) * N + n0 + tx];
    __syncthreads();
#pragma unroll
    for (int i = 0; i < 32; i += 8)
        dst[(size_t)(n0 + ty + i) * K + k0 + tx] = f2b(tile[tx][ty + i]);
}

// ---------------- init: X f32 -> xf f32 copy + xb bf16 ----------------
__global__ __launch_bounds__(256) void init_x(
    const float* __restrict__ X, float* __restrict__ xf, ushort_t* __restrict__ xb)
{
    const int i = blockIdx.x * 256 + threadIdx.x;
    const float4 v = ((const float4*)X)[i];
    ((float4*)xf)[i] = v;
    us4 o = { f2b(v.x), f2b(v.y), f2b(v.z), f2b(v.w) };
    ((us4*)xb)[i] = o;
}

// ---------------- GEMM: C[M][N] = A[M][K] @ Wt[N][K]^T, fused epilogues ----
enum { EPI_QKV = 0, EPI_RESF32 = 1, EPI_RELUB = 2 };

template<int EPI>
__global__ __launch_bounds__(256) void gemm128(
    const ushort_t* __restrict__ A, const ushort_t* __restrict__ Wt,
    const float* __restrict__ bias, const float* resid,
    float* Cf, ushort_t* __restrict__ Cb,
    ushort_t* __restrict__ Oq, ushort_t* __restrict__ Ok, ushort_t* __restrict__ Ov,
    int M, int N, int K)
{
    __shared__ ushort_t lA[128 * 32];
    __shared__ ushort_t lB[128 * 32];
    const int nbm = M >> 7;
    const int bm = blockIdx.x % nbm;
    const int bn = blockIdx.x / nbm;
    const int tid = threadIdx.x;
    const int lane = tid & 63, wave = tid >> 6;
    const int wr = wave >> 1, wc = wave & 1;
    const int l15 = lane & 15, l4 = lane >> 4;

    f32x4 acc[4][4];
#pragma unroll
    for (int i = 0; i < 4; i++)
#pragma unroll
        for (int j = 0; j < 4; j++) { f32x4 z = {0.f, 0.f, 0.f, 0.f}; acc[i][j] = z; }

    const int srow = tid >> 2, schunk = tid & 3;
    const ushort_t* Ab = A + (size_t)bm * 128 * K;
    const ushort_t* Bb = Wt + (size_t)bn * 128 * K;
    char* lAc = (char*)lA;
    char* lBc = (char*)lB;

    for (int k0 = 0; k0 < K; k0 += 32) {
        gload_lds16((const char*)(Ab + (size_t)srow * K + k0) + schunk * 16, lAc + wave * 1024);
        gload_lds16((const char*)(Ab + (size_t)(srow + 64) * K + k0) + schunk * 16, lAc + 4096 + wave * 1024);
        gload_lds16((const char*)(Bb + (size_t)srow * K + k0) + schunk * 16, lBc + wave * 1024);
        gload_lds16((const char*)(Bb + (size_t)(srow + 64) * K + k0) + schunk * 16, lBc + 4096 + wave * 1024);
        __syncthreads();
        bf16x8 af[4], bfr[4];
#pragma unroll
        for (int i = 0; i < 4; i++) {
            af[i]  = *(const bf16x8*)(lAc + (wr * 64 + i * 16 + l15) * 64 + l4 * 16);
            bfr[i] = *(const bf16x8*)(lBc + (wc * 64 + i * 16 + l15) * 64 + l4 * 16);
        }
#pragma unroll
        for (int i = 0; i < 4; i++)
#pragma unroll
            for (int j = 0; j < 4; j++)
                acc[i][j] = __builtin_amdgcn_mfma_f32_16x16x32_bf16(af[i], bfr[j], acc[i][j], 0, 0, 0);
        __syncthreads();
    }

    const int mbase = bm * 128 + wr * 64;
    const int nbase = bn * 128 + wc * 64;
#pragma unroll
    for (int j = 0; j < 4; j++) {
        const int nf16 = nbase + j * 16;
        const float bv = bias[nf16 + l15];
        if constexpr (EPI == EPI_QKV) {
            const int head = nf16 / 192;
            const int rem = nf16 - head * 192;
            const int part = rem >> 6;
            const int dh = (rem & 63) + l15;
#pragma unroll
            for (int i = 0; i < 4; i++) {
                const int m0 = mbase + i * 16 + l4 * 4;
#pragma unroll
                for (int r = 0; r < 4; r++) {
                    const int m = m0 + r;
                    const int b = m >> 11, s = m & 2047;
                    const float v = acc[i][j][r] + bv;
                    if (part == 0)
                        Oq[((size_t)(b * 8 + head) * 2048 + s) * 64 + dh] = f2b(v);
                    else if (part == 1)
                        Ok[((size_t)(b * 8 + head) * 2048 + s) * 64 + dh] = f2b(v);
                    else
                        Ov[((size_t)(b * 8 + head) * 64 + dh) * 2048 + s] = f2b(v);
                }
            }
        } else if constexpr (EPI == EPI_RESF32) {
#pragma unroll
            for (int i = 0; i < 4; i++) {
                const int m0 = mbase + i * 16 + l4 * 4;
#pragma unroll
                for (int r = 0; r < 4; r++) {
                    const size_t idx = (size_t)(m0 + r) * N + nf16 + l15;
                    Cf[idx] = acc[i][j][r] + bv + resid[idx];
                }
            }
        } else {
#pragma unroll
            for (int i = 0; i < 4; i++) {
                const int m0 = mbase + i * 16 + l4 * 4;
#pragma unroll
                for (int r = 0; r < 4; r++) {
                    const size_t idx = (size_t)(m0 + r) * N + nf16 + l15;
                    const float v = acc[i][j][r] + bv;
                    Cb[idx] = f2b(v > 0.f ? v : 0.f);
                }
            }
        }
    }
}

// ---------------- flash attention ----------------
// Q,K: [16][2048][64] bf16 ; Vt: [16][64][2048] bf16 ; O: [4096][512] bf16
__global__ __launch_bounds__(256) void flash_attn(
    const ushort_t* __restrict__ Q, const ushort_t* __restrict__ Kb,
    const ushort_t* __restrict__ Vt, ushort_t* __restrict__ O, float scale)
{
    __shared__ ushort_t lK[32 * 64];
    __shared__ ushort_t lV[64 * 32];
    __shared__ ushort_t lP[4][32 * 32];
    const int bh = blockIdx.y, qt = blockIdx.x;
    const int tid = threadIdx.x, lane = tid & 63, wave = tid >> 6;
    const int l15 = lane & 15, l4 = lane >> 4;
    const int qrow0 = qt * 128 + wave * 32;

    bf16x8 qf[2][2];
    {
        const ushort_t* Qb = Q + ((size_t)bh * 2048 + qrow0) * 64;
#pragma unroll
        for (int mi = 0; mi < 2; mi++)
#pragma unroll
            for (int ks = 0; ks < 2; ks++)
                qf[mi][ks] = *(const bf16x8*)(Qb + (mi * 16 + l15) * 64 + ks * 32 + l4 * 8);
    }

    float m_run[2][4], l_run[2][4];
    f32x4 oacc[2][4];
#pragma unroll
    for (int mi = 0; mi < 2; mi++)
#pragma unroll
        for (int r = 0; r < 4; r++) { m_run[mi][r] = -1e30f; l_run[mi][r] = 0.f; }
#pragma unroll
    for (int mi = 0; mi < 2; mi++)
#pragma unroll
        for (int nd = 0; nd < 4; nd++) { f32x4 z = {0.f, 0.f, 0.f, 0.f}; oacc[mi][nd] = z; }

    const int kkey = tid >> 3, kc = tid & 7;
    const int vdh = tid >> 2, vc = tid & 3;
    const ushort_t* Kbase = Kb + (size_t)bh * 2048 * 64;
    const ushort_t* Vbase = Vt + (size_t)bh * 64 * 2048;
    char* lKc = (char*)lK;
    char* lVc = (char*)lV;
    char* myP = (char*)(lP[wave]);

    for (int kt = 0; kt < 64; kt++) {
        gload_lds16((const char*)(Kbase + (size_t)(kt * 32 + kkey) * 64) + ((kc ^ (kkey & 7)) * 16),
                    lKc + wave * 1024);
        gload_lds16((const char*)(Vbase + (size_t)vdh * 2048 + kt * 32) + ((vc ^ ((vdh >> 1) & 3)) * 16),
                    lVc + wave * 1024);
        __syncthreads();

        f32x4 sc[2][2];
#pragma unroll
        for (int mi = 0; mi < 2; mi++)
#pragma unroll
            for (int nf = 0; nf < 2; nf++) { f32x4 z = {0.f, 0.f, 0.f, 0.f}; sc[mi][nf] = z; }

        bf16x8 kf[2][2];
#pragma unroll
        for (int nf = 0; nf < 2; nf++)
#pragma unroll
            for (int ks = 0; ks < 2; ks++) {
                const int key = nf * 16 + l15;
                const int chunk = ks * 4 + l4;
                kf[nf][ks] = *(const bf16x8*)(lKc + key * 128 + ((chunk ^ (key & 7)) * 16));
            }
#pragma unroll
        for (int mi = 0; mi < 2; mi++)
#pragma unroll
            for (int nf = 0; nf < 2; nf++)
#pragma unroll
                for (int ks = 0; ks < 2; ks++)
                    sc[mi][nf] = __builtin_amdgcn_mfma_f32_16x16x32_bf16(qf[mi][ks], kf[nf][ks], sc[mi][nf], 0, 0, 0);

#pragma unroll
        for (int mi = 0; mi < 2; mi++)
#pragma unroll
            for (int nf = 0; nf < 2; nf++)
#pragma unroll
                for (int r = 0; r < 4; r++)
                    sc[mi][nf][r] *= scale;

#pragma unroll
        for (int mi = 0; mi < 2; mi++) {
#pragma unroll
            for (int r = 0; r < 4; r++) {
                float v = fmaxf(sc[mi][0][r], sc[mi][1][r]);
                v = fmaxf(v, __shfl_xor(v, 1));
                v = fmaxf(v, __shfl_xor(v, 2));
                v = fmaxf(v, __shfl_xor(v, 4));
                v = fmaxf(v, __shfl_xor(v, 8));
                const float mn = fmaxf(m_run[mi][r], v);
                const float corr = __expf(m_run[mi][r] - mn);
                m_run[mi][r] = mn;
                const float p0 = __expf(sc[mi][0][r] - mn);
                const float p1 = __expf(sc[mi][1][r] - mn);
                sc[mi][0][r] = p0;
                sc[mi][1][r] = p1;
                float rs = p0 + p1;
                rs += __shfl_xor(rs, 1);
                rs += __shfl_xor(rs, 2);
                rs += __shfl_xor(rs, 4);
                rs += __shfl_xor(rs, 8);
                l_run[mi][r] = l_run[mi][r] * corr + rs;
#pragma unroll
                for (int nd = 0; nd < 4; nd++) oacc[mi][nd][r] *= corr;
            }
        }

        // P -> LDS (swizzled), then PV
#pragma unroll
        for (int mi = 0; mi < 2; mi++)
#pragma unroll
            for (int nf = 0; nf < 2; nf++)
#pragma unroll
                for (int r = 0; r < 4; r++) {
                    const int row = mi * 16 + l4 * 4 + r;
                    const int colb = (nf * 16 + l15) * 2;
                    *(ushort_t*)(myP + row * 64 + (colb ^ (((row >> 1) & 3) << 4))) = f2b(sc[mi][nf][r]);
                }
        __asm__ volatile("" ::: "memory");
        bf16x8 pf[2], vf[4];
#pragma unroll
        for (int mi = 0; mi < 2; mi++) {
            const int row = mi * 16 + l15;
            pf[mi] = *(const bf16x8*)(myP + row * 64 + ((l4 * 16) ^ ((((row >> 1) & 3)) << 4)));
        }
#pragma unroll
        for (int nd = 0; nd < 4; nd++) {
            const int dh = nd * 16 + l15;
            vf[nd] = *(const bf16x8*)(lVc + dh * 64 + ((l4 * 16) ^ (((dh >> 1) & 3) << 4)));
        }
#pragma unroll
        for (int mi = 0; mi < 2; mi++)
#pragma unroll
            for (int nd = 0; nd < 4; nd++)
                oacc[mi][nd] = __builtin_amdgcn_mfma_f32_16x16x32_bf16(pf[mi], vf[nd], oacc[mi][nd], 0, 0, 0);
        __syncthreads();
    }

    const int bq = bh >> 3, hh = bh & 7;
#pragma unroll
    for (int mi = 0; mi < 2; mi++)
#pragma unroll
        for (int r = 0; r < 4; r++) {
            const int s = qrow0 + mi * 16 + l4 * 4 + r;
            const float inv = 1.f / l_run[mi][r];
#pragma unroll
            for (int nd = 0; nd < 4; nd++)
                O[((size_t)(bq * 2048 + s)) * 512 + hh * 64 + nd * 16 + l15] = f2b(oacc[mi][nd][r] * inv);
        }
}

// ---------------- layernorm over D=512, 1 wave per row ----------------
__global__ __launch_bounds__(256) void layernorm512(
    const float* X, const float* __restrict__ g, const float* __restrict__ bta,
    ushort_t* __restrict__ Yb, float* Yf)
{
    const int row = blockIdx.x * 4 + (threadIdx.x >> 6);
    const int lane = threadIdx.x & 63;
    const float4* xp = (const float4*)(X + (size_t)row * 512);
    const float4 v0 = xp[lane];
    const float4 v1 = xp[lane + 64];
    float s = v0.x + v0.y + v0.z + v0.w + v1.x + v1.y + v1.z + v1.w;
    float s2 = v0.x * v0.x + v0.y * v0.y + v0.z * v0.z + v0.w * v0.w
             + v1.x * v1.x + v1.y * v1.y + v1.z * v1.z + v1.w * v1.w;
#pragma unroll
    for (int m = 1; m < 64; m <<= 1) { s += __shfl_xor(s, m); s2 += __shfl_xor(s2, m); }
    const float mean = s * (1.f / 512.f);
    const float inv = rsqrtf(s2 * (1.f / 512.f) - mean * mean + 1e-5f);
    const float4 g0 = ((const float4*)g)[lane], g1 = ((const float4*)g)[lane + 64];
    const float4 b0 = ((const float4*)bta)[lane], b1 = ((const float4*)bta)[lane + 64];
    float4 y0, y1;
    y0.x = (v0.x - mean) * inv * g0.x + b0.x;
    y0.y = (v0.y - mean) * inv * g0.y + b0.y;
    y0.z = (v0.z - mean) * inv * g0.z + b0.z;
    y0.w = (v0.w - mean) * inv * g0.w + b0.w;
    y1.x = (v1.x - mean) * inv * g1.x + b1.x;
    y1.y = (v1.y - mean) * inv * g1.y + b1.y;
    y1.z = (v1.z - mean) * inv * g1.z + b1.z;
    y1.w = (v1.w - mean) * inv * g1.w + b1.w;
    if (Yf) {
        ((float4*)(Yf + (size_t)row * 512))[lane] = y0;
        ((float4*)(Yf + (size_t)row * 512))[lane + 64] = y1;
    }
    us4 o0 = { f2b(y0.x), f2b(y0.y), f2b(y0.z), f2b(y0.w) };
    us4 o1 = { f2b(y1.x), f2b(y1.y), f2b(y1.z), f2b(y1.w) };
    ((us4*)(Yb + (size_t)row * 512))[lane] = o0;
    ((us4*)(Yb + (size_t)row * 512))[lane + 64] = o1;
}

// ---------------- host ----------------
extern "C" void kernel_launch(void* const* d_in, const int* in_sizes, int n_in,
                              void* d_out, int out_size, void* d_ws, size_t ws_size,
                              hipStream_t stream)
{
    (void)in_sizes; (void)n_in; (void)out_size; (void)ws_size;
    const float* X     = (const float*)d_in[0];
    const float* qkv_w = (const float*)d_in[1];
    const float* qkv_b = (const float*)d_in[2];
    const float* fc_w  = (const float*)d_in[3];
    const float* fc_b  = (const float*)d_in[4];
    const float* ln1_g = (const float*)d_in[5];
    const float* ln1_b = (const float*)d_in[6];
    const float* w1    = (const float*)d_in[7];
    const float* b1    = (const float*)d_in[8];
    const float* w2    = (const float*)d_in[9];
    const float* b2    = (const float*)d_in[10];
    const float* ln2_g = (const float*)d_in[11];
    const float* ln2_b = (const float*)d_in[12];

    char* ws = (char*)d_ws;
    size_t off = 0;
    auto alloc = [&](size_t bytes) -> char* {
        char* p = ws + off;
        off += (bytes + 255) & ~(size_t)255;
        return p;
    };
    ushort_t* qkvw_t = (ushort_t*)alloc(12ull * 1536 * 512 * 2);
    ushort_t* fcw_t  = (ushort_t*)alloc(12ull * 512 * 512 * 2);
    ushort_t* w1_t   = (ushort_t*)alloc(12ull * 512 * 1024 * 2);
    ushort_t* w2_t   = (ushort_t*)alloc(12ull * 1024 * 512 * 2);
    float*    xf     = (float*)   alloc(4096ull * 512 * 4);
    ushort_t* xb     = (ushort_t*)alloc(4096ull * 512 * 2);
    ushort_t* qb     = (ushort_t*)alloc(16ull * 2048 * 64 * 2);
    ushort_t* kb     = (ushort_t*)alloc(16ull * 2048 * 64 * 2);
    ushort_t* vt     = (ushort_t*)alloc(16ull * 64 * 2048 * 2);
    ushort_t* ob     = (ushort_t*)alloc(4096ull * 512 * 2);
    ushort_t* y1     = (ushort_t*)alloc(4096ull * 512 * 2);
    ushort_t* hbuf   = (ushort_t*)alloc(4096ull * 1024 * 2);

    transpose_cvt<<<dim3(48, 16, 12), 256, 0, stream>>>(qkv_w, qkvw_t, 512, 1536);
    transpose_cvt<<<dim3(16, 16, 12), 256, 0, stream>>>(fc_w, fcw_t, 512, 512);
    transpose_cvt<<<dim3(32, 16, 12), 256, 0, stream>>>(w1, w1_t, 512, 1024);
    transpose_cvt<<<dim3(16, 32, 12), 256, 0, stream>>>(w2, w2_t, 1024, 512);
    init_x<<<2048, 256, 0, stream>>>(X, xf, xb);

    const float scale = 0.044194173824159216f; // 1/sqrt(512) per reference
    for (int nb = 0; nb < 12; nb++) {
        gemm128<EPI_QKV><<<32 * 12, 256, 0, stream>>>(
            xb, qkvw_t + (size_t)nb * 1536 * 512, qkv_b + nb * 1536,
            nullptr, nullptr, nullptr, qb, kb, vt, 4096, 1536, 512);
        flash_attn<<<dim3(16, 16), 256, 0, stream>>>(qb, kb, vt, ob, scale);
        gemm128<EPI_RESF32><<<32 * 4, 256, 0, stream>>>(
            ob, fcw_t + (size_t)nb * 512 * 512, fc_b + nb * 512,
            xf, xf, nullptr, nullptr, nullptr, nullptr, 4096, 512, 512);
        layernorm512<<<1024, 256, 0, stream>>>(xf, ln1_g + nb * 512, ln1_b + nb * 512, y1, nullptr);
        gemm128<EPI_RELUB><<<32 * 8, 256, 0, stream>>>(
            y1, w1_t + (size_t)nb * 1024 * 512, b1 + nb * 1024,
            nullptr, nullptr, hbuf, nullptr, nullptr, nullptr, 4096, 1024, 512);
        gemm128<EPI_RESF32><<<32 * 4, 256, 0, stream>>>(
            hbuf, w2_t + (size_t)nb * 512 * 1024, b2 + nb * 512,
            xf, xf, nullptr, nullptr, nullptr, nullptr, 4096, 512, 1024);
        layernorm512<<<1024, 256, 0, stream>>>(xf, ln2_g + nb * 512, ln2_b + nb * 512, xb,
                                               nb == 11 ? (float*)d_out : xf);
    }
}

// Round 2
// 1619.880 us; speedup vs baseline: 1.6987x; 1.6987x over previous
//
#include <hip/hip_runtime.h>

typedef unsigned short ushort_t;
typedef __attribute__((ext_vector_type(8))) short bf16x8;
typedef __attribute__((ext_vector_type(4))) float f32x4;
typedef __attribute__((ext_vector_type(4))) unsigned short us4;

#define DEV __device__ __forceinline__

DEV ushort_t f2b(float f) {
    union { float f; unsigned u; } x; x.f = f;
    unsigned r = (x.u + 0x7fffu + ((x.u >> 16) & 1u)) >> 16;
    return (ushort_t)r;
}

typedef void __attribute__((address_space(1)))* gp1;
typedef void __attribute__((address_space(3)))* sp3;
DEV void gload_lds16(const void* g, void* l) {
    __builtin_amdgcn_global_load_lds((gp1)g, (sp3)l, 16, 0, 0);
}

// ---------------- weight prep: f32 [K][N] -> bf16 [N][K] ----------------
__global__ __launch_bounds__(256) void transpose_cvt(
    const float* __restrict__ in, ushort_t* __restrict__ out, int K, int N)
{
    __shared__ float tile[32][33];
    const int nb = blockIdx.z;
    const float* src = in + (size_t)nb * K * N;
    ushort_t* dst = out + (size_t)nb * K * N;
    const int n0 = blockIdx.x * 32, k0 = blockIdx.y * 32;
    const int tx = threadIdx.x & 31, ty = threadIdx.x >> 5;
#pragma unroll
    for (int i = 0; i < 32; i += 8)
        tile[ty + i][tx] = src[(size_t)(k0 + ty + i) * N + n0 + tx];
    __syncthreads();
#pragma unroll
    for (int i = 0; i < 32; i += 8)
        dst[(size_t)(n0 + ty + i) * K + k0 + tx] = f2b(tile[tx][ty + i]);
}

// ---------------- init: X f32 -> xf f32 copy + xb bf16 ----------------
__global__ __launch_bounds__(256) void init_x(
    const float* __restrict__ X, float* __restrict__ xf, ushort_t* __restrict__ xb)
{
    const int i = blockIdx.x * 256 + threadIdx.x;
    const float4 v = ((const float4*)X)[i];
    ((float4*)xf)[i] = v;
    us4 o = { f2b(v.x), f2b(v.y), f2b(v.z), f2b(v.w) };
    ((us4*)xb)[i] = o;
}

// ---------------- GEMM 64x128 tile: C[M][N] = A[M][K] @ Wt[N][K]^T ----------
enum { EPI_QKV = 0, EPI_RESF32 = 1, EPI_RELUB = 2 };

template<int EPI>
__global__ __launch_bounds__(256, 2) void gemm64(
    const ushort_t* __restrict__ A, const ushort_t* __restrict__ Wt,
    const float* __restrict__ bias, const float* __restrict__ resid,
    float* __restrict__ Cf, ushort_t* __restrict__ Cb,
    ushort_t* __restrict__ Oq, ushort_t* __restrict__ Ok, ushort_t* __restrict__ Ov,
    int M, int N, int K)
{
    __shared__ __align__(16) ushort_t lA[2][64 * 32];
    __shared__ __align__(16) ushort_t lB[2][128 * 32];
    const int nbm = M >> 6;
    const int bm = blockIdx.x % nbm;
    const int bn = blockIdx.x / nbm;
    const int tid = threadIdx.x, lane = tid & 63, w = tid >> 6;
    const int l15 = lane & 15, l4 = lane >> 4;

    f32x4 acc[4][2];
#pragma unroll
    for (int i = 0; i < 4; i++)
#pragma unroll
        for (int j = 0; j < 2; j++) { f32x4 z = {0.f, 0.f, 0.f, 0.f}; acc[i][j] = z; }

    const int srow = tid >> 2;                       // local row 0..63
    const int schA = (tid & 3) ^ ((srow >> 1) & 3);  // pre-swizzled source chunk
    const ushort_t* Asrc  = A  + (size_t)(bm * 64  + srow) * K + schA * 8;
    const ushort_t* Bsrc0 = Wt + (size_t)(bn * 128 + srow) * K + schA * 8;
    const ushort_t* Bsrc1 = Wt + (size_t)(bn * 128 + srow + 64) * K + schA * 8;
    char* lAc = (char*)lA;
    char* lBc = (char*)lB;

#define GE_STAGE(buf, k0) do {                                      \
        gload_lds16(Asrc  + (k0), lAc + (buf) * 4096 + w * 1024);   \
        gload_lds16(Bsrc0 + (k0), lBc + (buf) * 8192 + w * 1024);   \
        gload_lds16(Bsrc1 + (k0), lBc + (buf) * 8192 + 4096 + w * 1024); \
    } while (0)

    GE_STAGE(0, 0);
    __syncthreads();

    const int nIt = K >> 5;
    int cur = 0;
    for (int it = 0; it < nIt; ++it) {
        if (it + 1 < nIt) GE_STAGE(cur ^ 1, (it + 1) * 32);
        bf16x8 af[4], bfr[2];
#pragma unroll
        for (int i = 0; i < 4; i++) {
            const int row = i * 16 + l15;
            af[i] = *(const bf16x8*)(lAc + cur * 4096 + row * 64 +
                                     ((l4 ^ ((row >> 1) & 3)) << 4));
        }
#pragma unroll
        for (int j = 0; j < 2; j++) {
            const int row = w * 32 + j * 16 + l15;
            bfr[j] = *(const bf16x8*)(lBc + cur * 8192 + row * 64 +
                                      ((l4 ^ ((row >> 1) & 3)) << 4));
        }
#pragma unroll
        for (int i = 0; i < 4; i++)
#pragma unroll
            for (int j = 0; j < 2; j++)
                acc[i][j] = __builtin_amdgcn_mfma_f32_16x16x32_bf16(af[i], bfr[j], acc[i][j], 0, 0, 0);
        __syncthreads();
        cur ^= 1;
    }
#undef GE_STAGE

    const int mbase = bm * 64;
    const int nbase = bn * 128 + w * 32;
#pragma unroll
    for (int j = 0; j < 2; j++) {
        const int nf16 = nbase + j * 16;
        const float bv = bias[nf16 + l15];
        if constexpr (EPI == EPI_QKV) {
            const int head = nf16 / 192;
            const int rem = nf16 - head * 192;
            const int part = rem >> 6;
            const int dh = (rem & 63) + l15;
#pragma unroll
            for (int i = 0; i < 4; i++) {
                const int m0 = mbase + i * 16 + l4 * 4;
#pragma unroll
                for (int r = 0; r < 4; r++) {
                    const int m = m0 + r;
                    const int b = m >> 11, s = m & 2047;
                    const float v = acc[i][j][r] + bv;
                    if (part == 0)
                        Oq[((size_t)(b * 8 + head) * 2048 + s) * 64 + dh] = f2b(v);
                    else if (part == 1)
                        Ok[((size_t)(b * 8 + head) * 2048 + s) * 64 + dh] = f2b(v);
                    else
                        Ov[((size_t)(b * 8 + head) * 64 + dh) * 2048 + s] = f2b(v);
                }
            }
        } else if constexpr (EPI == EPI_RESF32) {
#pragma unroll
            for (int i = 0; i < 4; i++) {
                const int m0 = mbase + i * 16 + l4 * 4;
#pragma unroll
                for (int r = 0; r < 4; r++) {
                    const size_t idx = (size_t)(m0 + r) * N + nf16 + l15;
                    Cf[idx] = acc[i][j][r] + bv + resid[idx];
                }
            }
        } else {
#pragma unroll
            for (int i = 0; i < 4; i++) {
                const int m0 = mbase + i * 16 + l4 * 4;
#pragma unroll
                for (int r = 0; r < 4; r++) {
                    const size_t idx = (size_t)(m0 + r) * N + nf16 + l15;
                    const float v = acc[i][j][r] + bv;
                    Cb[idx] = f2b(v > 0.f ? v : 0.f);
                }
            }
        }
    }
}

// ---------------- flash attention v2 ----------------
// Q,K: [16][2048][64] bf16 ; Vt: [16][64][2048] bf16 ; O: [4096][512] bf16
// 512 blocks, 4 waves/block, 16 q-rows/wave, KVBLK=64, double-buffered K/V.
__global__ __launch_bounds__(256, 2) void flash_attn2(
    const ushort_t* __restrict__ Q, const ushort_t* __restrict__ Kg,
    const ushort_t* __restrict__ Vg, ushort_t* __restrict__ O, float sl2)
{
    __shared__ __align__(16) ushort_t lK[2][64 * 64];
    __shared__ __align__(16) ushort_t lV[2][64 * 64];
    __shared__ __align__(16) ushort_t lP[4][16 * 64];

    // XCD-clustered decode: blocks of one head land on one XCD (id%8 fixed).
    const int id = blockIdx.x;
    const int xcd = id & 7, rest = id >> 3;
    const int qt = rest & 31;
    const int bh = xcd + ((rest >> 5) << 3);   // 0..15
    const int tid = threadIdx.x, lane = tid & 63, w = tid >> 6;
    const int l15 = lane & 15, l4 = lane >> 4;
    const int qrow0 = qt * 64 + w * 16;

    const ushort_t* Qb = Q + ((size_t)bh * 2048 + qrow0) * 64;
    bf16x8 qf[2];
#pragma unroll
    for (int ks = 0; ks < 2; ks++)
        qf[ks] = *(const bf16x8*)(Qb + l15 * 64 + ks * 32 + l4 * 8);

    const ushort_t* Kbase = Kg + (size_t)bh * 2048 * 64;
    const ushort_t* Vbase = Vg + (size_t)bh * 64 * 2048;

    float m_run[4], l_run[4];
    f32x4 oacc[4];
#pragma unroll
    for (int r = 0; r < 4; r++) { m_run[r] = -1e30f; l_run[r] = 0.f; }
#pragma unroll
    for (int nd = 0; nd < 4; nd++) { f32x4 z = {0.f, 0.f, 0.f, 0.f}; oacc[nd] = z; }

    char* lKc = (char*)lK;
    char* lVc = (char*)lV;
    char* myP = (char*)(lP[w]);

    const int srow8 = lane >> 3;   // 0..7
    const int sch = lane & 7;

#define FA_STAGE(buf, kt) do {                                              \
        const int row0_ = w * 16 + srow8;                                   \
        const int sc0_ = sch ^ (row0_ & 7);                                 \
        gload_lds16(Kbase + (size_t)((kt) * 64 + row0_) * 64 + sc0_ * 8,    \
                    lKc + (buf) * 8192 + w * 2048);                         \
        gload_lds16(Vbase + (size_t)row0_ * 2048 + (kt) * 64 + sc0_ * 8,    \
                    lVc + (buf) * 8192 + w * 2048);                         \
        gload_lds16(Kbase + (size_t)((kt) * 64 + row0_ + 8) * 64 + sc0_ * 8,\
                    lKc + (buf) * 8192 + w * 2048 + 1024);                  \
        gload_lds16(Vbase + (size_t)(row0_ + 8) * 2048 + (kt) * 64 + sc0_ * 8,\
                    lVc + (buf) * 8192 + w * 2048 + 1024);                  \
    } while (0)

    FA_STAGE(0, 0);
    __syncthreads();

    int cur = 0;
    for (int kt = 0; kt < 32; kt++) {
        if (kt < 31) FA_STAGE(cur ^ 1, kt + 1);

        // QK^T over 64 keys
        f32x4 sc4[4];
#pragma unroll
        for (int nf = 0; nf < 4; nf++) { f32x4 z = {0.f, 0.f, 0.f, 0.f}; sc4[nf] = z; }
#pragma unroll
        for (int nf = 0; nf < 4; nf++) {
            const int krow = nf * 16 + l15;
#pragma unroll
            for (int ks = 0; ks < 2; ks++) {
                const bf16x8 kf = *(const bf16x8*)(lKc + cur * 8192 + krow * 128 +
                                                   (((ks * 4 + l4) ^ (krow & 7)) << 4));
                sc4[nf] = __builtin_amdgcn_mfma_f32_16x16x32_bf16(qf[ks], kf, sc4[nf], 0, 0, 0);
            }
        }

        // online softmax, log2 domain; l-reduction deferred to epilogue
#pragma unroll
        for (int nf = 0; nf < 4; nf++)
#pragma unroll
            for (int r = 0; r < 4; r++) sc4[nf][r] *= sl2;
#pragma unroll
        for (int r = 0; r < 4; r++) {
            float mx = fmaxf(fmaxf(sc4[0][r], sc4[1][r]), fmaxf(sc4[2][r], sc4[3][r]));
            mx = fmaxf(mx, __shfl_xor(mx, 1));
            mx = fmaxf(mx, __shfl_xor(mx, 2));
            mx = fmaxf(mx, __shfl_xor(mx, 4));
            mx = fmaxf(mx, __shfl_xor(mx, 8));
            const float mn = fmaxf(m_run[r], mx);
            const float corr = exp2f(m_run[r] - mn);
            m_run[r] = mn;
            float ps = 0.f;
#pragma unroll
            for (int nf = 0; nf < 4; nf++) {
                const float p = exp2f(sc4[nf][r] - mn);
                sc4[nf][r] = p;
                ps += p;
            }
            l_run[r] = l_run[r] * corr + ps;
#pragma unroll
            for (int nd = 0; nd < 4; nd++) oacc[nd][r] *= corr;
        }

        // P -> per-wave LDS (swizzled)
#pragma unroll
        for (int nf = 0; nf < 4; nf++) {
            const int key = nf * 16 + l15;
            const int ch = key >> 3, off = (key & 7) * 2;
#pragma unroll
            for (int r = 0; r < 4; r++) {
                const int row = l4 * 4 + r;
                *(ushort_t*)(myP + row * 128 + (((ch ^ (row & 7)) << 4) | off)) = f2b(sc4[nf][r]);
            }
        }

        // PV
#pragma unroll
        for (int kk = 0; kk < 2; kk++) {
            const bf16x8 pf = *(const bf16x8*)(myP + l15 * 128 +
                                               (((kk * 4 + l4) ^ (l15 & 7)) << 4));
#pragma unroll
            for (int nd = 0; nd < 4; nd++) {
                const int vrow = nd * 16 + l15;
                const bf16x8 vf = *(const bf16x8*)(lVc + cur * 8192 + vrow * 128 +
                                                   (((kk * 4 + l4) ^ (vrow & 7)) << 4));
                oacc[nd] = __builtin_amdgcn_mfma_f32_16x16x32_bf16(pf, vf, oacc[nd], 0, 0, 0);
            }
        }
        __syncthreads();
        cur ^= 1;
    }
#undef FA_STAGE

    const int bq = bh >> 3, hh = bh & 7;
#pragma unroll
    for (int r = 0; r < 4; r++) {
        float lr = l_run[r];
        lr += __shfl_xor(lr, 1);
        lr += __shfl_xor(lr, 2);
        lr += __shfl_xor(lr, 4);
        lr += __shfl_xor(lr, 8);
        const float inv = 1.f / lr;
        const int s = qrow0 + l4 * 4 + r;
#pragma unroll
        for (int nd = 0; nd < 4; nd++)
            O[((size_t)(bq * 2048 + s)) * 512 + hh * 64 + nd * 16 + l15] = f2b(oacc[nd][r] * inv);
    }
}

// ---------------- layernorm over D=512, 1 wave per row ----------------
__global__ __launch_bounds__(256) void layernorm512(
    const float* X, const float* __restrict__ g, const float* __restrict__ bta,
    ushort_t* __restrict__ Yb, float* Yf)
{
    const int row = blockIdx.x * 4 + (threadIdx.x >> 6);
    const int lane = threadIdx.x & 63;
    const float4* xp = (const float4*)(X + (size_t)row * 512);
    const float4 v0 = xp[lane];
    const float4 v1 = xp[lane + 64];
    float s = v0.x + v0.y + v0.z + v0.w + v1.x + v1.y + v1.z + v1.w;
    float s2 = v0.x * v0.x + v0.y * v0.y + v0.z * v0.z + v0.w * v0.w
             + v1.x * v1.x + v1.y * v1.y + v1.z * v1.z + v1.w * v1.w;
#pragma unroll
    for (int m = 1; m < 64; m <<= 1) { s += __shfl_xor(s, m); s2 += __shfl_xor(s2, m); }
    const float mean = s * (1.f / 512.f);
    const float inv = rsqrtf(s2 * (1.f / 512.f) - mean * mean + 1e-5f);
    const float4 g0 = ((const float4*)g)[lane], g1 = ((const float4*)g)[lane + 64];
    const float4 b0 = ((const float4*)bta)[lane], b1 = ((const float4*)bta)[lane + 64];
    float4 y0, y1;
    y0.x = (v0.x - mean) * inv * g0.x + b0.x;
    y0.y = (v0.y - mean) * inv * g0.y + b0.y;
    y0.z = (v0.z - mean) * inv * g0.z + b0.z;
    y0.w = (v0.w - mean) * inv * g0.w + b0.w;
    y1.x = (v1.x - mean) * inv * g1.x + b1.x;
    y1.y = (v1.y - mean) * inv * g1.y + b1.y;
    y1.z = (v1.z - mean) * inv * g1.z + b1.z;
    y1.w = (v1.w - mean) * inv * g1.w + b1.w;
    if (Yf) {
        ((float4*)(Yf + (size_t)row * 512))[lane] = y0;
        ((float4*)(Yf + (size_t)row * 512))[lane + 64] = y1;
    }
    us4 o0 = { f2b(y0.x), f2b(y0.y), f2b(y0.z), f2b(y0.w) };
    us4 o1 = { f2b(y1.x), f2b(y1.y), f2b(y1.z), f2b(y1.w) };
    ((us4*)(Yb + (size_t)row * 512))[lane] = o0;
    ((us4*)(Yb + (size_t)row * 512))[lane + 64] = o1;
}

// ---------------- host ----------------
extern "C" void kernel_launch(void* const* d_in, const int* in_sizes, int n_in,
                              void* d_out, int out_size, void* d_ws, size_t ws_size,
                              hipStream_t stream)
{
    (void)in_sizes; (void)n_in; (void)out_size; (void)ws_size;
    const float* X     = (const float*)d_in[0];
    const float* qkv_w = (const float*)d_in[1];
    const float* qkv_b = (const float*)d_in[2];
    const float* fc_w  = (const float*)d_in[3];
    const float* fc_b  = (const float*)d_in[4];
    const float* ln1_g = (const float*)d_in[5];
    const float* ln1_b = (const float*)d_in[6];
    const float* w1    = (const float*)d_in[7];
    const float* b1    = (const float*)d_in[8];
    const float* w2    = (const float*)d_in[9];
    const float* b2    = (const float*)d_in[10];
    const float* ln2_g = (const float*)d_in[11];
    const float* ln2_b = (const float*)d_in[12];

    char* ws = (char*)d_ws;
    size_t off = 0;
    auto alloc = [&](size_t bytes) -> char* {
        char* p = ws + off;
        off += (bytes + 255) & ~(size_t)255;
        return p;
    };
    ushort_t* qkvw_t = (ushort_t*)alloc(12ull * 1536 * 512 * 2);
    ushort_t* fcw_t  = (ushort_t*)alloc(12ull * 512 * 512 * 2);
    ushort_t* w1_t   = (ushort_t*)alloc(12ull * 512 * 1024 * 2);
    ushort_t* w2_t   = (ushort_t*)alloc(12ull * 1024 * 512 * 2);
    float*    xf     = (float*)   alloc(4096ull * 512 * 4);
    ushort_t* xb     = (ushort_t*)alloc(4096ull * 512 * 2);
    ushort_t* qb     = (ushort_t*)alloc(16ull * 2048 * 64 * 2);
    ushort_t* kb     = (ushort_t*)alloc(16ull * 2048 * 64 * 2);
    ushort_t* vt     = (ushort_t*)alloc(16ull * 64 * 2048 * 2);
    ushort_t* ob     = (ushort_t*)alloc(4096ull * 512 * 2);
    ushort_t* y1     = (ushort_t*)alloc(4096ull * 512 * 2);
    ushort_t* hbuf   = (ushort_t*)alloc(4096ull * 1024 * 2);

    transpose_cvt<<<dim3(48, 16, 12), 256, 0, stream>>>(qkv_w, qkvw_t, 512, 1536);
    transpose_cvt<<<dim3(16, 16, 12), 256, 0, stream>>>(fc_w, fcw_t, 512, 512);
    transpose_cvt<<<dim3(32, 16, 12), 256, 0, stream>>>(w1, w1_t, 512, 1024);
    transpose_cvt<<<dim3(16, 32, 12), 256, 0, stream>>>(w2, w2_t, 1024, 512);
    init_x<<<2048, 256, 0, stream>>>(X, xf, xb);

    const float sl2 = (float)(0.044194173824159216 * 1.4426950408889634); // scale * log2(e)
    for (int nb = 0; nb < 12; nb++) {
        gemm64<EPI_QKV><<<64 * 12, 256, 0, stream>>>(
            xb, qkvw_t + (size_t)nb * 1536 * 512, qkv_b + nb * 1536,
            nullptr, nullptr, nullptr, qb, kb, vt, 4096, 1536, 512);
        flash_attn2<<<512, 256, 0, stream>>>(qb, kb, vt, ob, sl2);
        gemm64<EPI_RESF32><<<64 * 4, 256, 0, stream>>>(
            ob, fcw_t + (size_t)nb * 512 * 512, fc_b + nb * 512,
            xf, xf, nullptr, nullptr, nullptr, nullptr, 4096, 512, 512);
        layernorm512<<<1024, 256, 0, stream>>>(xf, ln1_g + nb * 512, ln1_b + nb * 512, y1, nullptr);
        gemm64<EPI_RELUB><<<64 * 8, 256, 0, stream>>>(
            y1, w1_t + (size_t)nb * 1024 * 512, b1 + nb * 1024,
            nullptr, nullptr, hbuf, nullptr, nullptr, nullptr, 4096, 1024, 512);
        gemm64<EPI_RESF32><<<64 * 4, 256, 0, stream>>>(
            hbuf, w2_t + (size_t)nb * 1024 * 512, b2 + nb * 512,
            xf, xf, nullptr, nullptr, nullptr, nullptr, 4096, 512, 1024);
        layernorm512<<<1024, 256, 0, stream>>>(xf, ln2_g + nb * 512, ln2_b + nb * 512, xb,
                                               nb == 11 ? (float*)d_out : xf);
    }
}

// Round 3
// 1336.922 us; speedup vs baseline: 2.0583x; 1.2116x over previous
//
#include <hip/hip_runtime.h>

typedef unsigned short ushort_t;
typedef __attribute__((ext_vector_type(8))) short bf16x8;
typedef __attribute__((ext_vector_type(4))) float f32x4;
typedef __attribute__((ext_vector_type(4))) unsigned short us4;

#define DEV __device__ __forceinline__

DEV ushort_t f2b(float f) {
    union { float f; unsigned u; } x; x.f = f;
    unsigned r = (x.u + 0x7fffu + ((x.u >> 16) & 1u)) >> 16;
    return (ushort_t)r;
}

DEV unsigned cvt_pk_bf16(float lo, float hi) {
    unsigned r;
    asm("v_cvt_pk_bf16_f32 %0, %1, %2" : "=v"(r) : "v"(lo), "v"(hi));
    return r;
}

typedef void __attribute__((address_space(1)))* gp1;
typedef void __attribute__((address_space(3)))* sp3;
DEV void gload_lds16(const void* g, void* l) {
    __builtin_amdgcn_global_load_lds((gp1)g, (sp3)l, 16, 0, 0);
}

// ---------------- weight prep: f32 [K][N] -> bf16 [N][K] ----------------
__global__ __launch_bounds__(256) void transpose_cvt(
    const float* __restrict__ in, ushort_t* __restrict__ out, int K, int N)
{
    __shared__ float tile[32][33];
    const int nb = blockIdx.z;
    const float* src = in + (size_t)nb * K * N;
    ushort_t* dst = out + (size_t)nb * K * N;
    const int n0 = blockIdx.x * 32, k0 = blockIdx.y * 32;
    const int tx = threadIdx.x & 31, ty = threadIdx.x >> 5;
#pragma unroll
    for (int i = 0; i < 32; i += 8)
        tile[ty + i][tx] = src[(size_t)(k0 + ty + i) * N + n0 + tx];
    __syncthreads();
#pragma unroll
    for (int i = 0; i < 32; i += 8)
        dst[(size_t)(n0 + ty + i) * K + k0 + tx] = f2b(tile[tx][ty + i]);
}

// ---------------- init: X f32 -> xf f32 copy + xb bf16 ----------------
__global__ __launch_bounds__(256) void init_x(
    const float* __restrict__ X, float* __restrict__ xf, ushort_t* __restrict__ xb)
{
    const int i = blockIdx.x * 256 + threadIdx.x;
    const float4 v = ((const float4*)X)[i];
    ((float4*)xf)[i] = v;
    us4 o = { f2b(v.x), f2b(v.y), f2b(v.z), f2b(v.w) };
    ((us4*)xb)[i] = o;
}

// ---------------- GEMM 64x128 tile, BK=64: C = A[M][K] @ Wt[N][K]^T --------
enum { EPI_QKV = 0, EPI_RESF32 = 1, EPI_RELUB = 2 };

template<int EPI>
__global__ __launch_bounds__(256, 2) void gemm64(
    const ushort_t* __restrict__ A, const ushort_t* __restrict__ Wt,
    const float* __restrict__ bias, const float* __restrict__ resid,
    float* __restrict__ Cf, ushort_t* __restrict__ Cb,
    ushort_t* __restrict__ Oq, ushort_t* __restrict__ Ok, ushort_t* __restrict__ Ov,
    int M, int N, int K)
{
    __shared__ __align__(16) ushort_t lA[2][64 * 64];   // [row][64] 128B rows
    __shared__ __align__(16) ushort_t lB[2][128 * 64];
    const int nbm = M >> 6;
    const int bm = blockIdx.x % nbm;
    const int bn = blockIdx.x / nbm;
    const int tid = threadIdx.x, lane = tid & 63, w = tid >> 6;
    const int l15 = lane & 15, l4 = lane >> 4;

    f32x4 acc[4][2];
#pragma unroll
    for (int i = 0; i < 4; i++)
#pragma unroll
        for (int j = 0; j < 2; j++) { f32x4 z = {0.f, 0.f, 0.f, 0.f}; acc[i][j] = z; }

    // staging: 16B chunks, id = row*8 + ch; pre-swizzled source (ch ^ (row&7))
    const int srow = tid >> 3;           // 0..31
    const int sch = tid & 7;
    const int swch = sch ^ (srow & 7);   // (row+32k)&7 == row&7
    const ushort_t* Asrc0 = A  + (size_t)(bm * 64 + srow) * K + swch * 8;
    const ushort_t* Asrc1 = A  + (size_t)(bm * 64 + srow + 32) * K + swch * 8;
    const ushort_t* Bsrc0 = Wt + (size_t)(bn * 128 + srow) * K + swch * 8;
    const ushort_t* Bsrc1 = Wt + (size_t)(bn * 128 + srow + 32) * K + swch * 8;
    const ushort_t* Bsrc2 = Wt + (size_t)(bn * 128 + srow + 64) * K + swch * 8;
    const ushort_t* Bsrc3 = Wt + (size_t)(bn * 128 + srow + 96) * K + swch * 8;
    char* lAc = (char*)lA;
    char* lBc = (char*)lB;

#define GE_STAGE(buf, k0) do {                                            \
        gload_lds16(Asrc0 + (k0), lAc + (buf) * 8192  + w * 1024);        \
        gload_lds16(Asrc1 + (k0), lAc + (buf) * 8192  + 4096 + w * 1024); \
        gload_lds16(Bsrc0 + (k0), lBc + (buf) * 16384 + w * 1024);        \
        gload_lds16(Bsrc1 + (k0), lBc + (buf) * 16384 + 4096 + w * 1024); \
        gload_lds16(Bsrc2 + (k0), lBc + (buf) * 16384 + 8192 + w * 1024); \
        gload_lds16(Bsrc3 + (k0), lBc + (buf) * 16384 + 12288 + w * 1024);\
    } while (0)

    GE_STAGE(0, 0);
    __syncthreads();

    const int nIt = K >> 6;
    int cur = 0;
    for (int it = 0; it < nIt; ++it) {
        if (it + 1 < nIt) GE_STAGE(cur ^ 1, (it + 1) * 64);
#pragma unroll
        for (int ks = 0; ks < 2; ks++) {
            bf16x8 af[4], bfr[2];
#pragma unroll
            for (int i = 0; i < 4; i++) {
                const int row = i * 16 + l15;
                af[i] = *(const bf16x8*)(lAc + cur * 8192 + row * 128 +
                                         (((ks * 4 + l4) ^ (row & 7)) << 4));
            }
#pragma unroll
            for (int j = 0; j < 2; j++) {
                const int row = w * 32 + j * 16 + l15;
                bfr[j] = *(const bf16x8*)(lBc + cur * 16384 + row * 128 +
                                          (((ks * 4 + l4) ^ (row & 7)) << 4));
            }
#pragma unroll
            for (int i = 0; i < 4; i++)
#pragma unroll
                for (int j = 0; j < 2; j++)
                    acc[i][j] = __builtin_amdgcn_mfma_f32_16x16x32_bf16(af[i], bfr[j], acc[i][j], 0, 0, 0);
        }
        __syncthreads();
        cur ^= 1;
    }
#undef GE_STAGE

    const int mbase = bm * 64;
    const int nbase = bn * 128 + w * 32;
#pragma unroll
    for (int j = 0; j < 2; j++) {
        const int nf16 = nbase + j * 16;
        const float bv = bias[nf16 + l15];
        if constexpr (EPI == EPI_QKV) {
            const int head = nf16 / 192;
            const int rem = nf16 - head * 192;
            const int part = rem >> 6;
            const int dh = (rem & 63) + l15;
#pragma unroll
            for (int i = 0; i < 4; i++) {
                const int m0 = mbase + i * 16 + l4 * 4;
#pragma unroll
                for (int r = 0; r < 4; r++) {
                    const int m = m0 + r;
                    const int b = m >> 11, s = m & 2047;
                    const float v = acc[i][j][r] + bv;
                    if (part == 0)
                        Oq[((size_t)(b * 8 + head) * 2048 + s) * 64 + dh] = f2b(v);
                    else if (part == 1)
                        Ok[((size_t)(b * 8 + head) * 2048 + s) * 64 + dh] = f2b(v);
                    else
                        Ov[((size_t)(b * 8 + head) * 64 + dh) * 2048 + s] = f2b(v);
                }
            }
        } else if constexpr (EPI == EPI_RESF32) {
#pragma unroll
            for (int i = 0; i < 4; i++) {
                const int m0 = mbase + i * 16 + l4 * 4;
#pragma unroll
                for (int r = 0; r < 4; r++) {
                    const size_t idx = (size_t)(m0 + r) * N + nf16 + l15;
                    Cf[idx] = acc[i][j][r] + bv + resid[idx];
                }
            }
        } else {
#pragma unroll
            for (int i = 0; i < 4; i++) {
                const int m0 = mbase + i * 16 + l4 * 4;
#pragma unroll
                for (int r = 0; r < 4; r++) {
                    const size_t idx = (size_t)(m0 + r) * N + nf16 + l15;
                    const float v = acc[i][j][r] + bv;
                    Cb[idx] = f2b(v > 0.f ? v : 0.f);
                }
            }
        }
    }
}

// ---------------- flash attention v3: swapped QK^T + in-lane softmax -------
// Q,K: [16][2048][64] bf16 ; Vt: [16][64][2048] bf16 ; O: [4096][512] bf16
__global__ __launch_bounds__(256, 2) void flash_attn3(
    const ushort_t* __restrict__ Q, const ushort_t* __restrict__ Kg,
    const ushort_t* __restrict__ Vg, ushort_t* __restrict__ O, float sl2)
{
    __shared__ __align__(16) ushort_t lK[2][64 * 64];
    __shared__ __align__(16) ushort_t lV[2][64 * 64];
    __shared__ __align__(16) ushort_t lP[4][16 * 64];

    const int id = blockIdx.x;
    const int xcd = id & 7, rest = id >> 3;
    const int qt = rest & 31;
    const int bh = xcd + ((rest >> 5) << 3);
    const int tid = threadIdx.x, lane = tid & 63, w = tid >> 6;
    const int l15 = lane & 15, l4 = lane >> 4;
    const int qrow0 = qt * 64 + w * 16;

    const ushort_t* Qb = Q + ((size_t)bh * 2048 + qrow0) * 64;
    bf16x8 qf[2];
#pragma unroll
    for (int ks = 0; ks < 2; ks++)
        qf[ks] = *(const bf16x8*)(Qb + l15 * 64 + ks * 32 + l4 * 8);

    const ushort_t* Kbase = Kg + (size_t)bh * 2048 * 64;
    const ushort_t* Vbase = Vg + (size_t)bh * 64 * 2048;

    // per-lane state: this lane tracks q-row l15 (partial keys: its l4 slice)
    float m_run = -100000.f;  // raw-score domain
    float l_run = 0.f;
    f32x4 oacc[4];
#pragma unroll
    for (int nd = 0; nd < 4; nd++) { f32x4 z = {0.f, 0.f, 0.f, 0.f}; oacc[nd] = z; }

    char* lKc = (char*)lK;
    char* lVc = (char*)lV;
    char* myP = (char*)(lP[w]);

    const int srow8 = lane >> 3;
    const int sch = lane & 7;

#define FA_STAGE(buf, kt) do {                                              \
        const int row0_ = w * 16 + srow8;                                   \
        const int sc0_ = sch ^ (row0_ & 7);                                 \
        gload_lds16(Kbase + (size_t)((kt) * 64 + row0_) * 64 + sc0_ * 8,    \
                    lKc + (buf) * 8192 + w * 2048);                         \
        gload_lds16(Vbase + (size_t)row0_ * 2048 + (kt) * 64 + sc0_ * 8,    \
                    lVc + (buf) * 8192 + w * 2048);                         \
        gload_lds16(Kbase + (size_t)((kt) * 64 + row0_ + 8) * 64 + sc0_ * 8,\
                    lKc + (buf) * 8192 + w * 2048 + 1024);                  \
        gload_lds16(Vbase + (size_t)(row0_ + 8) * 2048 + (kt) * 64 + sc0_ * 8,\
                    lVc + (buf) * 8192 + w * 2048 + 1024);                  \
    } while (0)

    FA_STAGE(0, 0);
    __syncthreads();

    int cur = 0;
    for (int kt = 0; kt < 32; kt++) {
        if (kt < 31) FA_STAGE(cur ^ 1, kt + 1);

        // QK^T, swapped operands: sc[key][qrow]; lane holds keys nf*16+l4*4+r
        // for q-row l15.
        f32x4 sc4[4];
#pragma unroll
        for (int nf = 0; nf < 4; nf++) { f32x4 z = {0.f, 0.f, 0.f, 0.f}; sc4[nf] = z; }
#pragma unroll
        for (int nf = 0; nf < 4; nf++) {
            const int krow = nf * 16 + l15;
#pragma unroll
            for (int ks = 0; ks < 2; ks++) {
                const bf16x8 kf = *(const bf16x8*)(lKc + cur * 8192 + krow * 128 +
                                                   (((ks * 4 + l4) ^ (krow & 7)) << 4));
                sc4[nf] = __builtin_amdgcn_mfma_f32_16x16x32_bf16(kf, qf[ks], sc4[nf], 0, 0, 0);
            }
        }

        // in-lane max over 16 raw scores + 2 cross-lane hops (l4 groups)
        float mx = fmaxf(fmaxf(sc4[0][0], sc4[0][1]), fmaxf(sc4[0][2], sc4[0][3]));
#pragma unroll
        for (int nf = 1; nf < 4; nf++)
            mx = fmaxf(mx, fmaxf(fmaxf(sc4[nf][0], sc4[nf][1]),
                                 fmaxf(sc4[nf][2], sc4[nf][3])));
        mx = fmaxf(mx, __shfl_xor(mx, 16));
        mx = fmaxf(mx, __shfl_xor(mx, 32));

        // defer-max: rescale only when max grows past 2^8 headroom
        const int need = (mx > m_run + 125.f) ? 1 : 0;
        if (__any(need)) {
            const float mn = fmaxf(m_run, mx);
            const float corr = exp2f((m_run - mn) * sl2);
            m_run = mn;
            l_run *= corr;
            float cr[4];
#pragma unroll
            for (int r = 0; r < 4; r++) cr[r] = __shfl(corr, l4 * 4 + r);
#pragma unroll
            for (int nd = 0; nd < 4; nd++)
#pragma unroll
                for (int r = 0; r < 4; r++) oacc[nd][r] *= cr[r];
        }

        // p = 2^(sc*sl2 - m*sl2), in-lane sum into l_run (cross-lane deferred)
        const float msl = m_run * sl2;
        float ps = 0.f;
#pragma unroll
        for (int nf = 0; nf < 4; nf++)
#pragma unroll
            for (int r = 0; r < 4; r++) {
                const float p = exp2f(sc4[nf][r] * sl2 - msl);
                sc4[nf][r] = p;
                ps += p;
            }
        l_run += ps;

        // pack pairs, write P[qrow=l15][key] as swizzled b32
#pragma unroll
        for (int nf = 0; nf < 4; nf++)
#pragma unroll
            for (int h = 0; h < 2; h++) {
                const unsigned pw = cvt_pk_bf16(sc4[nf][2 * h], sc4[nf][2 * h + 1]);
                const int colb = nf * 32 + l4 * 8 + h * 4;
                *(unsigned*)(myP + l15 * 128 + (colb ^ ((l15 & 7) << 4))) = pw;
            }
        __asm__ volatile("" ::: "memory");

        // PV: pa = P rows (A operand), vf = V cols (B operand)
        bf16x8 pa[2];
#pragma unroll
        for (int ks = 0; ks < 2; ks++)
            pa[ks] = *(const bf16x8*)(myP + l15 * 128 +
                                      ((ks * 64 + l4 * 16) ^ ((l15 & 7) << 4)));
#pragma unroll
        for (int ks = 0; ks < 2; ks++)
#pragma unroll
            for (int nd = 0; nd < 4; nd++) {
                const int vrow = nd * 16 + l15;
                const bf16x8 vf = *(const bf16x8*)(lVc + cur * 8192 + vrow * 128 +
                                                   (((ks * 4 + l4) ^ (vrow & 7)) << 4));
                oacc[nd] = __builtin_amdgcn_mfma_f32_16x16x32_bf16(pa[ks], vf, oacc[nd], 0, 0, 0);
            }
        __syncthreads();
        cur ^= 1;
    }
#undef FA_STAGE

    // epilogue: finish l reduce (cross-lane), fetch per-O-row inverse
    l_run += __shfl_xor(l_run, 16);
    l_run += __shfl_xor(l_run, 32);
    const int bq = bh >> 3, hh = bh & 7;
#pragma unroll
    for (int r = 0; r < 4; r++) {
        const float lr = __shfl(l_run, l4 * 4 + r);
        const float inv = 1.f / lr;
        const int s = qrow0 + l4 * 4 + r;
#pragma unroll
        for (int nd = 0; nd < 4; nd++)
            O[((size_t)(bq * 2048 + s)) * 512 + hh * 64 + nd * 16 + l15] = f2b(oacc[nd][r] * inv);
    }
}

// ---------------- layernorm over D=512, 1 wave per row ----------------
__global__ __launch_bounds__(256) void layernorm512(
    const float* X, const float* __restrict__ g, const float* __restrict__ bta,
    ushort_t* __restrict__ Yb, float* Yf)
{
    const int row = blockIdx.x * 4 + (threadIdx.x >> 6);
    const int lane = threadIdx.x & 63;
    const float4* xp = (const float4*)(X + (size_t)row * 512);
    const float4 v0 = xp[lane];
    const float4 v1 = xp[lane + 64];
    float s = v0.x + v0.y + v0.z + v0.w + v1.x + v1.y + v1.z + v1.w;
    float s2 = v0.x * v0.x + v0.y * v0.y + v0.z * v0.z + v0.w * v0.w
             + v1.x * v1.x + v1.y * v1.y + v1.z * v1.z + v1.w * v1.w;
#pragma unroll
    for (int m = 1; m < 64; m <<= 1) { s += __shfl_xor(s, m); s2 += __shfl_xor(s2, m); }
    const float mean = s * (1.f / 512.f);
    const float inv = rsqrtf(s2 * (1.f / 512.f) - mean * mean + 1e-5f);
    const float4 g0 = ((const float4*)g)[lane], g1 = ((const float4*)g)[lane + 64];
    const float4 b0 = ((const float4*)bta)[lane], b1 = ((const float4*)bta)[lane + 64];
    float4 y0, y1;
    y0.x = (v0.x - mean) * inv * g0.x + b0.x;
    y0.y = (v0.y - mean) * inv * g0.y + b0.y;
    y0.z = (v0.z - mean) * inv * g0.z + b0.z;
    y0.w = (v0.w - mean) * inv * g0.w + b0.w;
    y1.x = (v1.x - mean) * inv * g1.x + b1.x;
    y1.y = (v1.y - mean) * inv * g1.y + b1.y;
    y1.z = (v1.z - mean) * inv * g1.z + b1.z;
    y1.w = (v1.w - mean) * inv * g1.w + b1.w;
    if (Yf) {
        ((float4*)(Yf + (size_t)row * 512))[lane] = y0;
        ((float4*)(Yf + (size_t)row * 512))[lane + 64] = y1;
    }
    us4 o0 = { f2b(y0.x), f2b(y0.y), f2b(y0.z), f2b(y0.w) };
    us4 o1 = { f2b(y1.x), f2b(y1.y), f2b(y1.z), f2b(y1.w) };
    ((us4*)(Yb + (size_t)row * 512))[lane] = o0;
    ((us4*)(Yb + (size_t)row * 512))[lane + 64] = o1;
}

// ---------------- host ----------------
extern "C" void kernel_launch(void* const* d_in, const int* in_sizes, int n_in,
                              void* d_out, int out_size, void* d_ws, size_t ws_size,
                              hipStream_t stream)
{
    (void)in_sizes; (void)n_in; (void)out_size; (void)ws_size;
    const float* X     = (const float*)d_in[0];
    const float* qkv_w = (const float*)d_in[1];
    const float* qkv_b = (const float*)d_in[2];
    const float* fc_w  = (const float*)d_in[3];
    const float* fc_b  = (const float*)d_in[4];
    const float* ln1_g = (const float*)d_in[5];
    const float* ln1_b = (const float*)d_in[6];
    const float* w1    = (const float*)d_in[7];
    const float* b1    = (const float*)d_in[8];
    const float* w2    = (const float*)d_in[9];
    const float* b2    = (const float*)d_in[10];
    const float* ln2_g = (const float*)d_in[11];
    const float* ln2_b = (const float*)d_in[12];

    char* ws = (char*)d_ws;
    size_t off = 0;
    auto alloc = [&](size_t bytes) -> char* {
        char* p = ws + off;
        off += (bytes + 255) & ~(size_t)255;
        return p;
    };
    ushort_t* qkvw_t = (ushort_t*)alloc(12ull * 1536 * 512 * 2);
    ushort_t* fcw_t  = (ushort_t*)alloc(12ull * 512 * 512 * 2);
    ushort_t* w1_t   = (ushort_t*)alloc(12ull * 512 * 1024 * 2);
    ushort_t* w2_t   = (ushort_t*)alloc(12ull * 1024 * 512 * 2);
    float*    xf     = (float*)   alloc(4096ull * 512 * 4);
    ushort_t* xb     = (ushort_t*)alloc(4096ull * 512 * 2);
    ushort_t* qb     = (ushort_t*)alloc(16ull * 2048 * 64 * 2);
    ushort_t* kb     = (ushort_t*)alloc(16ull * 2048 * 64 * 2);
    ushort_t* vt     = (ushort_t*)alloc(16ull * 64 * 2048 * 2);
    ushort_t* ob     = (ushort_t*)alloc(4096ull * 512 * 2);
    ushort_t* y1     = (ushort_t*)alloc(4096ull * 512 * 2);
    ushort_t* hbuf   = (ushort_t*)alloc(4096ull * 1024 * 2);

    transpose_cvt<<<dim3(48, 16, 12), 256, 0, stream>>>(qkv_w, qkvw_t, 512, 1536);
    transpose_cvt<<<dim3(16, 16, 12), 256, 0, stream>>>(fc_w, fcw_t, 512, 512);
    transpose_cvt<<<dim3(32, 16, 12), 256, 0, stream>>>(w1, w1_t, 512, 1024);
    transpose_cvt<<<dim3(16, 32, 12), 256, 0, stream>>>(w2, w2_t, 1024, 512);
    init_x<<<2048, 256, 0, stream>>>(X, xf, xb);

    const float sl2 = (float)(0.044194173824159216 * 1.4426950408889634); // scale*log2(e)
    for (int nb = 0; nb < 12; nb++) {
        gemm64<EPI_QKV><<<64 * 12, 256, 0, stream>>>(
            xb, qkvw_t + (size_t)nb * 1536 * 512, qkv_b + nb * 1536,
            nullptr, nullptr, nullptr, qb, kb, vt, 4096, 1536, 512);
        flash_attn3<<<512, 256, 0, stream>>>(qb, kb, vt, ob, sl2);
        gemm64<EPI_RESF32><<<64 * 4, 256, 0, stream>>>(
            ob, fcw_t + (size_t)nb * 512 * 512, fc_b + nb * 512,
            xf, xf, nullptr, nullptr, nullptr, nullptr, 4096, 512, 512);
        layernorm512<<<1024, 256, 0, stream>>>(xf, ln1_g + nb * 512, ln1_b + nb * 512, y1, nullptr);
        gemm64<EPI_RELUB><<<64 * 8, 256, 0, stream>>>(
            y1, w1_t + (size_t)nb * 1024 * 512, b1 + nb * 1024,
            nullptr, nullptr, hbuf, nullptr, nullptr, nullptr, 4096, 1024, 512);
        gemm64<EPI_RESF32><<<64 * 4, 256, 0, stream>>>(
            hbuf, w2_t + (size_t)nb * 1024 * 512, b2 + nb * 512,
            xf, xf, nullptr, nullptr, nullptr, nullptr, 4096, 512, 1024);
        layernorm512<<<1024, 256, 0, stream>>>(xf, ln2_g + nb * 512, ln2_b + nb * 512, xb,
                                               nb == 11 ? (float*)d_out : xf);
    }
}